// Round 3
// baseline (664.458 us; speedup 1.0000x reference)
//
#include <hip/hip_runtime.h>
#include <hip/hip_bf16.h>

#define N_NODES 40000
#define M_PAD   40064
#define N_EDGES 320000
#define DIM 128
#define HC 512
#define NHEAD 4
#define CHEAD 128
#define DEPTH_L 2
#define MLP_DIM 512

typedef __attribute__((ext_vector_type(8))) short short8;
typedef __attribute__((ext_vector_type(4))) float f32x4;

static __device__ __forceinline__ void gload_lds16(const void* g, void* l)
{
    __builtin_amdgcn_global_load_lds(
        (const __attribute__((address_space(1))) unsigned int*)g,
        (__attribute__((address_space(3))) unsigned int*)l,
        16, 0, 0);
}

// ---------------- LayerNorm: one wave per row, bf16 output -------------------
__global__ __launch_bounds__(256) void k_ln(const float* __restrict__ x,
                                            const float* __restrict__ gma,
                                            const float* __restrict__ bta,
                                            __hip_bfloat16* __restrict__ out, int M)
{
    int row = blockIdx.x * 4 + (threadIdx.x >> 6);
    int lane = threadIdx.x & 63;
    if (row >= M) return;
    float2 v = *reinterpret_cast<const float2*>(x + (size_t)row * DIM + lane * 2);
    float s = v.x + v.y, sq = v.x * v.x + v.y * v.y;
    #pragma unroll
    for (int d = 32; d; d >>= 1) { s += __shfl_xor(s, d); sq += __shfl_xor(sq, d); }
    float mean = s * (1.f / DIM);
    float var = sq * (1.f / DIM) - mean * mean;
    float rs = rsqrtf(var + 1e-5f);
    int c = lane * 2;
    union { __hip_bfloat16 b[2]; unsigned int u; } p;
    p.b[0] = __float2bfloat16((v.x - mean) * rs * gma[c] + bta[c]);
    p.b[1] = __float2bfloat16((v.y - mean) * rs * gma[c + 1] + bta[c + 1]);
    *reinterpret_cast<unsigned int*>(out + (size_t)row * DIM + c) = p.u;
}

// ---------------- weight convert + transpose: W[K][N] f32 -> Wt[N][K] bf16 ---
__global__ __launch_bounds__(256) void k_wcvt(const float* __restrict__ W,
                                              __hip_bfloat16* __restrict__ Wt,
                                              int K, int N)
{
    int i = blockIdx.x * 256 + threadIdx.x;
    if (i < K * N) {
        int n = i / K, k = i % K;
        Wt[i] = __float2bfloat16(W[(size_t)k * N + n]);
    }
}

// ---------------- bf16 MFMA GEMM: C[M,N] = A[M,K] @ Bt[N,K]^T ----------------
// BMt x 128 tile, BK=64, 4 waves. XOR-swizzled LDS (slot = g ^ (r&7)) staged
// via global_load_lds w=16 with inverse-swizzled global source.
// MODE: 0 = bf16 out + fused att dots   1 = bf16 out, bias+gelu
//       2 = f32 out, bias+resid
template <int MODE, int BMt>
__global__ __launch_bounds__(256) void k_mm(const short* __restrict__ A,
                                            const short* __restrict__ Bt,
                                            const float* __restrict__ bias,
                                            const float* __restrict__ resid,
                                            void* __restrict__ Cout,
                                            const float* __restrict__ av,
                                            const float* __restrict__ dv,
                                            float* __restrict__ asrcO,
                                            float* __restrict__ adstO,
                                            int M, int N, int K)
{
    constexpr int FI = BMt / 32;            // fragment rows per wave (4 or 2)
    __shared__ __align__(16) short Als[BMt * 64];
    __shared__ __align__(16) short Bls[128 * 64];
    const int tid = threadIdx.x;
    const int lane = tid & 63;
    const int w = tid >> 6;
    const int wr = w >> 1, wc = w & 1;
    const int lrow = lane & 15;
    const int lk = lane >> 4;
    const int m0 = blockIdx.x * BMt;
    const int n0 = blockIdx.y * 128;

    f32x4 acc[FI][4] = {};

    for (int kt = 0; kt < K; kt += 64) {
        #pragma unroll
        for (int c0 = 0; c0 < BMt * 8 + 1024; c0 += 256) {
            int c = c0 + tid;
            int wb = c0 + (w << 6);              // wave-uniform chunk base
            if (wb < BMt * 8) {
                int r = c >> 3, gq = c & 7, gp = gq ^ (r & 7);
                gload_lds16(A + (size_t)(m0 + r) * K + kt + gp * 8, &Als[wb * 8]);
            } else {
                int cc = c - BMt * 8;
                int r = cc >> 3, gq = cc & 7, gp = gq ^ (r & 7);
                gload_lds16(Bt + (size_t)(n0 + r) * K + kt + gp * 8,
                            &Bls[(wb - BMt * 8) * 8]);
            }
        }
        __syncthreads();

        #pragma unroll
        for (int ks = 0; ks < 2; ++ks) {
            short8 af[FI], bf[4];
            #pragma unroll
            for (int fi = 0; fi < FI; ++fi) {
                int r = wr * (FI * 16) + fi * 16 + lrow;
                int g = ks * 4 + lk;
                af[fi] = *reinterpret_cast<const short8*>(&Als[r * 64 + (g ^ (r & 7)) * 8]);
            }
            #pragma unroll
            for (int fj = 0; fj < 4; ++fj) {
                int r = wc * 64 + fj * 16 + lrow;
                int g = ks * 4 + lk;
                bf[fj] = *reinterpret_cast<const short8*>(&Bls[r * 64 + (g ^ (r & 7)) * 8]);
            }
            #pragma unroll
            for (int fi = 0; fi < FI; ++fi)
                #pragma unroll
                for (int fj = 0; fj < 4; ++fj)
                    acc[fi][fj] = __builtin_amdgcn_mfma_f32_16x16x32_bf16(
                        af[fi], bf[fj], acc[fi][fj], 0, 0, 0);
        }
        __syncthreads();
    }

    // epilogue: C/D layout col = lane&15, row = (lane>>4)*4 + p
    #pragma unroll
    for (int fi = 0; fi < FI; ++fi) {
        #pragma unroll
        for (int fj = 0; fj < 4; ++fj) {
            #pragma unroll
            for (int p = 0; p < 4; ++p) {
                int m = m0 + wr * (FI * 16) + fi * 16 + lk * 4 + p;
                int n = n0 + wc * 64 + fj * 16 + lrow;
                if (m >= M) continue;
                float v = acc[fi][fj][p];
                if (MODE == 0) {
                    ((__hip_bfloat16*)Cout)[(size_t)m * N + n] = __float2bfloat16(v);
                } else if (MODE == 1) {
                    v += bias[n];
                    float u = v;
                    v = 0.5f * u * (1.f + tanhf(0.7978845608f * (u + 0.044715f * u * u * u)));
                    ((__hip_bfloat16*)Cout)[(size_t)m * N + n] = __float2bfloat16(v);
                } else {
                    v += bias[n] + resid[(size_t)m * N + n];
                    ((float*)Cout)[(size_t)m * N + n] = v;
                }
            }
        }
    }

    // fused per-node attention dots: asrc[m,h] += sum_c h[m,c]*a_src[h,c]
    if (MODE == 0) {
        float avv[4], dvv[4];
        #pragma unroll
        for (int fj = 0; fj < 4; ++fj) {
            int col = n0 + wc * 64 + fj * 16 + lrow;
            avv[fj] = av[col];
            dvv[fj] = dv[col];
        }
        int hh = n0 >> 7;
        #pragma unroll
        for (int fi = 0; fi < FI; ++fi) {
            #pragma unroll
            for (int p = 0; p < 4; ++p) {
                int m = m0 + wr * (FI * 16) + fi * 16 + lk * 4 + p;
                float s1 = 0.f, s2 = 0.f;
                #pragma unroll
                for (int fj = 0; fj < 4; ++fj) {
                    s1 += acc[fi][fj][p] * avv[fj];
                    s2 += acc[fi][fj][p] * dvv[fj];
                }
                #pragma unroll
                for (int d = 1; d < 16; d <<= 1) {
                    s1 += __shfl_xor(s1, d);
                    s2 += __shfl_xor(s2, d);
                }
                if (lrow == 0 && m < M) {
                    atomicAdd(&asrcO[m * 4 + hh], s1);
                    atomicAdd(&adstO[m * 4 + hh], s2);
                }
            }
        }
    }
}

__global__ void k_ae(const float* __restrict__ We, const float* __restrict__ a_edge,
                     float* __restrict__ ae)
{
    int h = threadIdx.x >> 6, lane = threadIdx.x & 63;
    float2 w = *reinterpret_cast<const float2*>(We + h * CHEAD + lane * 2);
    float2 a = *reinterpret_cast<const float2*>(a_edge + h * CHEAD + lane * 2);
    float s = w.x * a.x + w.y * a.y;
    #pragma unroll
    for (int d = 32; d; d >>= 1) s += __shfl_xor(s, d);
    if (lane == 0) ae[h] = s;
}

// ---------------- CSR build ---------------------------------------------------
__global__ void k_hist(const int* __restrict__ dst, int* __restrict__ deg)
{
    int e = blockIdx.x * 256 + threadIdx.x;
    if (e < N_EDGES) atomicAdd(&deg[dst[e]], 1);
}

__global__ __launch_bounds__(1024) void k_scan(const int* __restrict__ deg,
                                               int* __restrict__ off, int n)
{
    __shared__ int wsum[16];
    __shared__ int carry;
    int t = threadIdx.x, lane = t & 63, w = t >> 6;
    if (t == 0) carry = 0;
    __syncthreads();
    for (int base = 0; base < n; base += 1024) {
        int i = base + t;
        int v = (i < n) ? deg[i] : 0;
        int s = v;
        #pragma unroll
        for (int d = 1; d < 64; d <<= 1) {
            int u = __shfl_up(s, d);
            if (lane >= d) s += u;
        }
        if (lane == 63) wsum[w] = s;
        __syncthreads();
        int wpre = 0;
        for (int j = 0; j < w; j++) wpre += wsum[j];
        int c0 = carry;
        if (i < n) off[i] = c0 + wpre + s - v;
        __syncthreads();
        if (t == 1023) carry = c0 + wpre + s;
        __syncthreads();
    }
    if (t == 0) off[n] = carry;
}

__global__ void k_cursor(const int* __restrict__ off, int* __restrict__ cur)
{
    int n = blockIdx.x * 256 + threadIdx.x;
    if (n < N_NODES) cur[n] = off[n];
}

// fill CSR: scsr[p] = src[e], pos[e] = p
__global__ void k_fill(const int* __restrict__ src, const int* __restrict__ dst,
                       int* __restrict__ cur, int* __restrict__ scsr,
                       int* __restrict__ pos)
{
    int e = blockIdx.x * 256 + threadIdx.x;
    if (e < N_EDGES) {
        int p = atomicAdd(&cur[dst[e]], 1);
        scsr[p] = src[e];
        pos[e] = p;
    }
}

// ---------------- per-edge weights: w = exp(lrelu(asrc+adst+ae*ea)) ----------
__global__ __launch_bounds__(256) void k_alpha(const int* __restrict__ src,
                                               const int* __restrict__ dst,
                                               const int* __restrict__ pos,
                                               const float* __restrict__ ea,
                                               const float* __restrict__ asrc,
                                               const float* __restrict__ adst,
                                               const float* __restrict__ ae4,
                                               float* __restrict__ wcsr,
                                               float* __restrict__ den)
{
    int e = blockIdx.x * 256 + threadIdx.x;
    if (e >= N_EDGES) return;
    int s = src[e], dd = dst[e], p = pos[e];
    float4 as = reinterpret_cast<const float4*>(asrc)[s];
    float4 ad = reinterpret_cast<const float4*>(adst)[dd];
    float4 ae = *reinterpret_cast<const float4*>(ae4);
    float eav = ea[e];
    float4 wv;
    float al;
    al = as.x + ad.x + ae.x * eav; al = al > 0.f ? al : 0.2f * al; wv.x = __expf(al);
    al = as.y + ad.y + ae.y * eav; al = al > 0.f ? al : 0.2f * al; wv.y = __expf(al);
    al = as.z + ad.z + ae.z * eav; al = al > 0.f ? al : 0.2f * al; wv.z = __expf(al);
    al = as.w + ad.w + ae.w * eav; al = al > 0.f ? al : 0.2f * al; wv.w = __expf(al);
    reinterpret_cast<float4*>(wcsr)[p] = wv;
    atomicAdd(&den[dd * 4 + 0], wv.x);
    atomicAdd(&den[dd * 4 + 1], wv.y);
    atomicAdd(&den[dd * 4 + 2], wv.z);
    atomicAdd(&den[dd * 4 + 3], wv.w);
}

// ---------------- single-pass aggregate: 4 nodes / 256-thread block ----------
__global__ __launch_bounds__(256) void k_agg(const int* __restrict__ off,
                                             const int* __restrict__ scsr,
                                             const float* __restrict__ wcsr,
                                             const float* __restrict__ den,
                                             const __hip_bfloat16* __restrict__ h2,
                                             const float* __restrict__ bias,
                                             __hip_bfloat16* __restrict__ g)
{
    int n = blockIdx.x * 4 + (threadIdx.x >> 6);
    int lane = threadIdx.x & 63;
    int h = lane >> 4;
    int cb = lane * 8;
    int e0 = off[n], e1 = off[n + 1];
    float inv = 1.f / (den[n * 4 + h] + 1e-16f);
    float acc[8] = {0, 0, 0, 0, 0, 0, 0, 0};
    int i = e0;
    for (; i + 1 < e1; i += 2) {
        int s0 = scsr[i], s1 = scsr[i + 1];
        float w0 = wcsr[i * 4 + h], w1 = wcsr[(i + 1) * 4 + h];
        uint4 v0 = *reinterpret_cast<const uint4*>(h2 + (size_t)s0 * HC + cb);
        uint4 v1 = *reinterpret_cast<const uint4*>(h2 + (size_t)s1 * HC + cb);
        float f[8];
        f[0] = __uint_as_float(v0.x << 16); f[1] = __uint_as_float(v0.x & 0xffff0000u);
        f[2] = __uint_as_float(v0.y << 16); f[3] = __uint_as_float(v0.y & 0xffff0000u);
        f[4] = __uint_as_float(v0.z << 16); f[5] = __uint_as_float(v0.z & 0xffff0000u);
        f[6] = __uint_as_float(v0.w << 16); f[7] = __uint_as_float(v0.w & 0xffff0000u);
        #pragma unroll
        for (int j = 0; j < 8; j++) acc[j] += w0 * f[j];
        f[0] = __uint_as_float(v1.x << 16); f[1] = __uint_as_float(v1.x & 0xffff0000u);
        f[2] = __uint_as_float(v1.y << 16); f[3] = __uint_as_float(v1.y & 0xffff0000u);
        f[4] = __uint_as_float(v1.z << 16); f[5] = __uint_as_float(v1.z & 0xffff0000u);
        f[6] = __uint_as_float(v1.w << 16); f[7] = __uint_as_float(v1.w & 0xffff0000u);
        #pragma unroll
        for (int j = 0; j < 8; j++) acc[j] += w1 * f[j];
    }
    if (i < e1) {
        int s0 = scsr[i];
        float w0 = wcsr[i * 4 + h];
        uint4 v0 = *reinterpret_cast<const uint4*>(h2 + (size_t)s0 * HC + cb);
        float f[8];
        f[0] = __uint_as_float(v0.x << 16); f[1] = __uint_as_float(v0.x & 0xffff0000u);
        f[2] = __uint_as_float(v0.y << 16); f[3] = __uint_as_float(v0.y & 0xffff0000u);
        f[4] = __uint_as_float(v0.z << 16); f[5] = __uint_as_float(v0.z & 0xffff0000u);
        f[6] = __uint_as_float(v0.w << 16); f[7] = __uint_as_float(v0.w & 0xffff0000u);
        #pragma unroll
        for (int j = 0; j < 8; j++) acc[j] += w0 * f[j];
    }
    union { uint4 u; __hip_bfloat16 b[8]; } o;
    #pragma unroll
    for (int j = 0; j < 8; j++) o.b[j] = __float2bfloat16(acc[j] * inv + bias[cb + j]);
    *reinterpret_cast<uint4*>(g + (size_t)n * HC + cb) = o.u;
}

extern "C" void kernel_launch(void* const* d_in, const int* in_sizes, int n_in,
                              void* d_out, int out_size, void* d_ws, size_t ws_size,
                              hipStream_t stream)
{
    const float* x_in     = (const float*)d_in[0];
    const int*   ei       = (const int*)d_in[1];
    const float* ea       = (const float*)d_in[2];
    const float* ln1_g    = (const float*)d_in[3];
    const float* ln1_b    = (const float*)d_in[4];
    const float* gat_W    = (const float*)d_in[5];
    const float* att_src  = (const float*)d_in[6];
    const float* att_dst  = (const float*)d_in[7];
    const float* edge_W   = (const float*)d_in[8];
    const float* att_edge = (const float*)d_in[9];
    const float* gat_bias = (const float*)d_in[10];
    const float* qf_W     = (const float*)d_in[11];
    const float* qf_b     = (const float*)d_in[12];
    const float* ln2_g    = (const float*)d_in[13];
    const float* ln2_b    = (const float*)d_in[14];
    const float* ff_W1    = (const float*)d_in[15];
    const float* ff_b1    = (const float*)d_in[16];
    const float* ff_W2    = (const float*)d_in[17];
    const float* ff_b2    = (const float*)d_in[18];
    float* x = (float*)d_out;

    char* ws = (char*)d_ws;
    size_t o = 0;
    auto alloc = [&](size_t b) { size_t r = o; o += (b + 255) & ~(size_t)255; return r; };
    __hip_bfloat16*  h_ln  = (__hip_bfloat16*)(ws + alloc((size_t)M_PAD * DIM * 2));
    __hip_bfloat16*  h2    = (__hip_bfloat16*)(ws + alloc((size_t)N_NODES * HC * 2));
    __hip_bfloat16*  gbuf  = (__hip_bfloat16*)(ws + alloc((size_t)M_PAD * HC * 2));
    float*           asrc  = (float*)(ws + alloc((size_t)N_NODES * 4 * 4));
    float*           adst  = (float*)(ws + alloc((size_t)N_NODES * 4 * 4));
    float*           den   = (float*)(ws + alloc((size_t)N_NODES * 4 * 4));
    float*           ae4   = (float*)(ws + alloc(256));
    int*             deg   = (int*)(ws + alloc((size_t)(N_NODES + 1) * 4));
    int*             off   = (int*)(ws + alloc((size_t)(N_NODES + 1) * 4));
    int*             cur   = (int*)(ws + alloc((size_t)N_NODES * 4));
    int*             scsr  = (int*)(ws + alloc((size_t)N_EDGES * 4));
    int*             pos   = (int*)(ws + alloc((size_t)N_EDGES * 4));
    float*           wcsr  = (float*)(ws + alloc((size_t)N_EDGES * 4 * 4));
    __hip_bfloat16* Wt[DEPTH_L][4];
    for (int d = 0; d < DEPTH_L; ++d)
        for (int j = 0; j < 4; ++j)
            Wt[d][j] = (__hip_bfloat16*)(ws + alloc((size_t)65536 * 2));

    const int* srcA = ei;
    const int* dstA = ei + N_EDGES;

    hipMemcpyAsync(x, x_in, (size_t)N_NODES * DIM * 4, hipMemcpyDeviceToDevice, stream);

    for (int d = 0; d < DEPTH_L; ++d) {
        k_wcvt<<<256, 256, 0, stream>>>(gat_W + (size_t)d * DIM * HC,  Wt[d][0], DIM, HC);
        k_wcvt<<<256, 256, 0, stream>>>(qf_W  + (size_t)d * HC * DIM,  Wt[d][1], HC, DIM);
        k_wcvt<<<256, 256, 0, stream>>>(ff_W1 + (size_t)d * DIM * MLP_DIM, Wt[d][2], DIM, MLP_DIM);
        k_wcvt<<<256, 256, 0, stream>>>(ff_W2 + (size_t)d * MLP_DIM * DIM, Wt[d][3], MLP_DIM, DIM);
    }

    // CSR by dst (edges identical across layers)
    hipMemsetAsync(deg, 0, (size_t)(N_NODES + 1) * 4, stream);
    k_hist<<<(N_EDGES + 255) / 256, 256, 0, stream>>>(dstA, deg);
    k_scan<<<1, 1024, 0, stream>>>(deg, off, N_NODES);
    k_cursor<<<(N_NODES + 255) / 256, 256, 0, stream>>>(off, cur);
    k_fill<<<(N_EDGES + 255) / 256, 256, 0, stream>>>(srcA, dstA, cur, scsr, pos);

    const int MB = (N_NODES + 127) / 128;   // 313
    const int MB64 = N_NODES / 64;          // 625
    for (int d = 0; d < DEPTH_L; ++d) {
        hipMemsetAsync(asrc, 0, (size_t)N_NODES * 16, stream);
        hipMemsetAsync(adst, 0, (size_t)N_NODES * 16, stream);
        hipMemsetAsync(den,  0, (size_t)N_NODES * 16, stream);
        // PreNorm + GAT
        k_ln<<<N_NODES / 4, 256, 0, stream>>>(x, ln1_g + d * DIM, ln1_b + d * DIM, h_ln, N_NODES);
        dim3 g1(MB, HC / 128);
        k_mm<0, 128><<<g1, 256, 0, stream>>>((const short*)h_ln, (const short*)Wt[d][0],
            nullptr, nullptr, h2,
            att_src + (size_t)d * HC, att_dst + (size_t)d * HC, asrc, adst,
            N_NODES, HC, DIM);
        k_ae<<<1, 256, 0, stream>>>(edge_W + d * HC, att_edge + d * NHEAD * CHEAD, ae4);
        k_alpha<<<(N_EDGES + 255) / 256, 256, 0, stream>>>(srcA, dstA, pos, ea,
            asrc, adst, ae4, wcsr, den);
        k_agg<<<N_NODES / 4, 256, 0, stream>>>(off, scsr, wcsr, den, h2,
            gat_bias + d * HC, gbuf);
        k_mm<2, 64><<<dim3(MB64, 1), 256, 0, stream>>>((const short*)gbuf, (const short*)Wt[d][1],
            qf_b + d * DIM, x, x, nullptr, nullptr, nullptr, nullptr, N_NODES, DIM, HC);
        // PreNorm + FF
        k_ln<<<N_NODES / 4, 256, 0, stream>>>(x, ln2_g + d * DIM, ln2_b + d * DIM, h_ln, N_NODES);
        k_mm<1, 128><<<g1, 256, 0, stream>>>((const short*)h_ln, (const short*)Wt[d][2],
            ff_b1 + d * MLP_DIM, nullptr, gbuf, nullptr, nullptr, nullptr, nullptr,
            N_NODES, MLP_DIM, DIM);
        k_mm<2, 64><<<dim3(MB64, 1), 256, 0, stream>>>((const short*)gbuf, (const short*)Wt[d][3],
            ff_b2 + d * DIM, x, x, nullptr, nullptr, nullptr, nullptr, N_NODES, DIM, MLP_DIM);
    }
}

// Round 4
// 564.485 us; speedup vs baseline: 1.1771x; 1.1771x over previous
//
#include <hip/hip_runtime.h>
#include <hip/hip_bf16.h>

#define N_NODES 40000
#define M_PAD   40064
#define N_EDGES 320000
#define DIM 128
#define HC 512
#define NHEAD 4
#define CHEAD 128
#define DEPTH_L 2
#define MLP_DIM 512

typedef __attribute__((ext_vector_type(8))) short short8;
typedef __attribute__((ext_vector_type(4))) float f32x4;

static __device__ __forceinline__ void gload_lds16(const void* g, void* l)
{
    __builtin_amdgcn_global_load_lds(
        (const __attribute__((address_space(1))) unsigned int*)g,
        (__attribute__((address_space(3))) unsigned int*)l,
        16, 0, 0);
}

// ---------------- LayerNorm: one wave per row, bf16 output -------------------
__global__ __launch_bounds__(256) void k_ln(const float* __restrict__ x,
                                            const float* __restrict__ gma,
                                            const float* __restrict__ bta,
                                            __hip_bfloat16* __restrict__ out, int M)
{
    int row = blockIdx.x * 4 + (threadIdx.x >> 6);
    int lane = threadIdx.x & 63;
    if (row >= M) return;
    float2 v = *reinterpret_cast<const float2*>(x + (size_t)row * DIM + lane * 2);
    float s = v.x + v.y, sq = v.x * v.x + v.y * v.y;
    #pragma unroll
    for (int d = 32; d; d >>= 1) { s += __shfl_xor(s, d); sq += __shfl_xor(sq, d); }
    float mean = s * (1.f / DIM);
    float var = sq * (1.f / DIM) - mean * mean;
    float rs = rsqrtf(var + 1e-5f);
    int c = lane * 2;
    union { __hip_bfloat16 b[2]; unsigned int u; } p;
    p.b[0] = __float2bfloat16((v.x - mean) * rs * gma[c] + bta[c]);
    p.b[1] = __float2bfloat16((v.y - mean) * rs * gma[c + 1] + bta[c + 1]);
    *reinterpret_cast<unsigned int*>(out + (size_t)row * DIM + c) = p.u;
}

// ---------------- weight convert + transpose: W[K][N] f32 -> Wt[N][K] bf16 ---
__global__ __launch_bounds__(256) void k_wcvt(const float* __restrict__ W,
                                              __hip_bfloat16* __restrict__ Wt,
                                              int K, int N)
{
    int i = blockIdx.x * 256 + threadIdx.x;
    if (i < K * N) {
        int n = i / K, k = i % K;
        Wt[i] = __float2bfloat16(W[(size_t)k * N + n]);
    }
}

// ---------------- bf16 MFMA GEMM: C[M,N] = A[M,K] @ Bt[N,K]^T ----------------
// BMt x 128 tile, BKt K-step, 4 waves. XOR-swizzled LDS (slot = c ^ (r&(CPR-1)))
// staged via global_load_lds w=16 with inverse-swizzled global source.
// MODE: 0 = bf16 out + fused att dots   1 = bf16 out, bias+gelu
//       2 = f32 out, bias+resid
template <int MODE, int BMt, int BKt>
__global__ __launch_bounds__(256) void k_mm(const short* __restrict__ A,
                                            const short* __restrict__ Bt,
                                            const float* __restrict__ bias,
                                            const float* __restrict__ resid,
                                            void* __restrict__ Cout,
                                            const float* __restrict__ av,
                                            const float* __restrict__ dv,
                                            float* __restrict__ asrcO,
                                            float* __restrict__ adstO,
                                            int M, int N, int K)
{
    constexpr int FI = BMt / 32;            // fragment rows per wave
    constexpr int KS = BKt / 32;            // K sub-steps
    constexpr int CPR = BKt / 8;            // 16B chunks per row
    constexpr int ACH = BMt * CPR;          // A chunks
    constexpr int BCH = 128 * CPR;          // B chunks
    __shared__ __align__(16) short Als[BMt * BKt];
    __shared__ __align__(16) short Bls[128 * BKt];
    const int tid = threadIdx.x;
    const int lane = tid & 63;
    const int w = tid >> 6;
    const int wr = w >> 1, wc = w & 1;
    const int lrow = lane & 15;
    const int lk = lane >> 4;
    const int m0 = blockIdx.x * BMt;
    const int n0 = blockIdx.y * 128;

    f32x4 acc[FI][4] = {};

    for (int kt = 0; kt < K; kt += BKt) {
        #pragma unroll
        for (int c0 = 0; c0 < ACH + BCH; c0 += 256) {
            int c = c0 + tid;
            int wb = c0 + (w << 6);              // wave-uniform chunk base
            if (wb < ACH) {
                int r = c / CPR, gq = c % CPR, gp = gq ^ (r & (CPR - 1));
                gload_lds16(A + (size_t)(m0 + r) * K + kt + gp * 8, &Als[wb * 8]);
            } else {
                int cc = c - ACH;
                int r = cc / CPR, gq = cc % CPR, gp = gq ^ (r & (CPR - 1));
                gload_lds16(Bt + (size_t)(n0 + r) * K + kt + gp * 8,
                            &Bls[(wb - ACH) * 8]);
            }
        }
        __syncthreads();

        #pragma unroll
        for (int ks = 0; ks < KS; ++ks) {
            short8 af[FI], bf[4];
            #pragma unroll
            for (int fi = 0; fi < FI; ++fi) {
                int r = wr * (FI * 16) + fi * 16 + lrow;
                int g = ks * 4 + lk;
                af[fi] = *reinterpret_cast<const short8*>(
                    &Als[r * BKt + (g ^ (r & (CPR - 1))) * 8]);
            }
            #pragma unroll
            for (int fj = 0; fj < 4; ++fj) {
                int r = wc * 64 + fj * 16 + lrow;
                int g = ks * 4 + lk;
                bf[fj] = *reinterpret_cast<const short8*>(
                    &Bls[r * BKt + (g ^ (r & (CPR - 1))) * 8]);
            }
            #pragma unroll
            for (int fi = 0; fi < FI; ++fi)
                #pragma unroll
                for (int fj = 0; fj < 4; ++fj)
                    acc[fi][fj] = __builtin_amdgcn_mfma_f32_16x16x32_bf16(
                        af[fi], bf[fj], acc[fi][fj], 0, 0, 0);
        }
        if (kt + BKt < K) __syncthreads();
    }

    // epilogue: C/D layout col = lane&15, row = (lane>>4)*4 + p
    #pragma unroll
    for (int fi = 0; fi < FI; ++fi) {
        #pragma unroll
        for (int fj = 0; fj < 4; ++fj) {
            #pragma unroll
            for (int p = 0; p < 4; ++p) {
                int m = m0 + wr * (FI * 16) + fi * 16 + lk * 4 + p;
                int n = n0 + wc * 64 + fj * 16 + lrow;
                if (m >= M) continue;
                float v = acc[fi][fj][p];
                if (MODE == 0) {
                    ((__hip_bfloat16*)Cout)[(size_t)m * N + n] = __float2bfloat16(v);
                } else if (MODE == 1) {
                    v += bias[n];
                    float u = v;
                    v = 0.5f * u * (1.f + tanhf(0.7978845608f * (u + 0.044715f * u * u * u)));
                    ((__hip_bfloat16*)Cout)[(size_t)m * N + n] = __float2bfloat16(v);
                } else {
                    v += bias[n] + resid[(size_t)m * N + n];
                    ((float*)Cout)[(size_t)m * N + n] = v;
                }
            }
        }
    }

    // fused per-node attention dots: asrc[m,h] += sum_c h[m,c]*a_src[h,c]
    if (MODE == 0) {
        float avv[4], dvv[4];
        #pragma unroll
        for (int fj = 0; fj < 4; ++fj) {
            int col = n0 + wc * 64 + fj * 16 + lrow;
            avv[fj] = av[col];
            dvv[fj] = dv[col];
        }
        int hh = n0 >> 7;
        #pragma unroll
        for (int fi = 0; fi < FI; ++fi) {
            #pragma unroll
            for (int p = 0; p < 4; ++p) {
                int m = m0 + wr * (FI * 16) + fi * 16 + lk * 4 + p;
                float s1 = 0.f, s2 = 0.f;
                #pragma unroll
                for (int fj = 0; fj < 4; ++fj) {
                    s1 += acc[fi][fj][p] * avv[fj];
                    s2 += acc[fi][fj][p] * dvv[fj];
                }
                #pragma unroll
                for (int d = 1; d < 16; d <<= 1) {
                    s1 += __shfl_xor(s1, d);
                    s2 += __shfl_xor(s2, d);
                }
                if (lrow == 0 && m < M) {
                    atomicAdd(&asrcO[m * 4 + hh], s1);
                    atomicAdd(&adstO[m * 4 + hh], s2);
                }
            }
        }
    }
}

__global__ void k_ae(const float* __restrict__ We, const float* __restrict__ a_edge,
                     float* __restrict__ ae)
{
    int h = threadIdx.x >> 6, lane = threadIdx.x & 63;
    float2 w = *reinterpret_cast<const float2*>(We + h * CHEAD + lane * 2);
    float2 a = *reinterpret_cast<const float2*>(a_edge + h * CHEAD + lane * 2);
    float s = w.x * a.x + w.y * a.y;
    #pragma unroll
    for (int d = 32; d; d >>= 1) s += __shfl_xor(s, d);
    if (lane == 0) ae[h] = s;
}

// ---------------- CSR build ---------------------------------------------------
__global__ void k_hist(const int* __restrict__ dst, int* __restrict__ deg)
{
    int e = blockIdx.x * 256 + threadIdx.x;
    if (e < N_EDGES) atomicAdd(&deg[dst[e]], 1);
}

__global__ __launch_bounds__(1024) void k_scan(const int* __restrict__ deg,
                                               int* __restrict__ off, int n)
{
    __shared__ int wsum[16];
    __shared__ int carry;
    int t = threadIdx.x, lane = t & 63, w = t >> 6;
    if (t == 0) carry = 0;
    __syncthreads();
    for (int base = 0; base < n; base += 1024) {
        int i = base + t;
        int v = (i < n) ? deg[i] : 0;
        int s = v;
        #pragma unroll
        for (int d = 1; d < 64; d <<= 1) {
            int u = __shfl_up(s, d);
            if (lane >= d) s += u;
        }
        if (lane == 63) wsum[w] = s;
        __syncthreads();
        int wpre = 0;
        for (int j = 0; j < w; j++) wpre += wsum[j];
        int c0 = carry;
        if (i < n) off[i] = c0 + wpre + s - v;
        __syncthreads();
        if (t == 1023) carry = c0 + wpre + s;
        __syncthreads();
    }
    if (t == 0) off[n] = carry;
}

__global__ void k_cursor(const int* __restrict__ off, int* __restrict__ cur)
{
    int n = blockIdx.x * 256 + threadIdx.x;
    if (n < N_NODES) cur[n] = off[n];
}

// fill CSR: scsr[p] = src[e], eacsr[p] = ea[e]  (edge_attr is layer-invariant)
__global__ void k_fill(const int* __restrict__ src, const int* __restrict__ dst,
                       const float* __restrict__ ea, int* __restrict__ cur,
                       int* __restrict__ scsr, float* __restrict__ eacsr)
{
    int e = blockIdx.x * 256 + threadIdx.x;
    if (e < N_EDGES) {
        int p = atomicAdd(&cur[dst[e]], 1);
        scsr[p] = src[e];
        eacsr[p] = ea[e];
    }
}

// ---------------- fused alpha + softmax + aggregate: 4 nodes / block ----------
// w_e = exp(lrelu(asrc[s]+adst[n]+ae[h]*ea_e)); out = (Σ w_e h2[s]) / (Σ w_e + eps)
__global__ __launch_bounds__(256) void k_agg(const int* __restrict__ off,
                                             const int* __restrict__ scsr,
                                             const float* __restrict__ eacsr,
                                             const float* __restrict__ asrc,
                                             const float* __restrict__ adst,
                                             const float* __restrict__ ae4,
                                             const __hip_bfloat16* __restrict__ h2,
                                             const float* __restrict__ bias,
                                             __hip_bfloat16* __restrict__ g)
{
    int n = blockIdx.x * 4 + (threadIdx.x >> 6);
    int lane = threadIdx.x & 63;
    int h = lane >> 4;
    int cb = lane * 8;
    int e0 = off[n], e1 = off[n + 1];
    float adh = adst[n * 4 + h];
    float aeh = ae4[h];
    float den = 0.f;
    float acc[8] = {0, 0, 0, 0, 0, 0, 0, 0};
    int i = e0;
    for (; i + 1 < e1; i += 2) {
        int s0 = scsr[i], s1 = scsr[i + 1];
        float ea0 = eacsr[i], ea1 = eacsr[i + 1];
        float a0 = asrc[s0 * 4 + h], a1 = asrc[s1 * 4 + h];
        uint4 v0 = *reinterpret_cast<const uint4*>(h2 + (size_t)s0 * HC + cb);
        uint4 v1 = *reinterpret_cast<const uint4*>(h2 + (size_t)s1 * HC + cb);
        float al0 = a0 + adh + aeh * ea0; al0 = al0 > 0.f ? al0 : 0.2f * al0;
        float al1 = a1 + adh + aeh * ea1; al1 = al1 > 0.f ? al1 : 0.2f * al1;
        float w0 = __expf(al0), w1 = __expf(al1);
        den += w0 + w1;
        float f[8];
        f[0] = __uint_as_float(v0.x << 16); f[1] = __uint_as_float(v0.x & 0xffff0000u);
        f[2] = __uint_as_float(v0.y << 16); f[3] = __uint_as_float(v0.y & 0xffff0000u);
        f[4] = __uint_as_float(v0.z << 16); f[5] = __uint_as_float(v0.z & 0xffff0000u);
        f[6] = __uint_as_float(v0.w << 16); f[7] = __uint_as_float(v0.w & 0xffff0000u);
        #pragma unroll
        for (int j = 0; j < 8; j++) acc[j] += w0 * f[j];
        f[0] = __uint_as_float(v1.x << 16); f[1] = __uint_as_float(v1.x & 0xffff0000u);
        f[2] = __uint_as_float(v1.y << 16); f[3] = __uint_as_float(v1.y & 0xffff0000u);
        f[4] = __uint_as_float(v1.z << 16); f[5] = __uint_as_float(v1.z & 0xffff0000u);
        f[6] = __uint_as_float(v1.w << 16); f[7] = __uint_as_float(v1.w & 0xffff0000u);
        #pragma unroll
        for (int j = 0; j < 8; j++) acc[j] += w1 * f[j];
    }
    if (i < e1) {
        int s0 = scsr[i];
        float al = asrc[s0 * 4 + h] + adh + aeh * eacsr[i];
        al = al > 0.f ? al : 0.2f * al;
        float w0 = __expf(al);
        den += w0;
        uint4 v0 = *reinterpret_cast<const uint4*>(h2 + (size_t)s0 * HC + cb);
        float f[8];
        f[0] = __uint_as_float(v0.x << 16); f[1] = __uint_as_float(v0.x & 0xffff0000u);
        f[2] = __uint_as_float(v0.y << 16); f[3] = __uint_as_float(v0.y & 0xffff0000u);
        f[4] = __uint_as_float(v0.z << 16); f[5] = __uint_as_float(v0.z & 0xffff0000u);
        f[6] = __uint_as_float(v0.w << 16); f[7] = __uint_as_float(v0.w & 0xffff0000u);
        #pragma unroll
        for (int j = 0; j < 8; j++) acc[j] += w0 * f[j];
    }
    float inv = 1.f / (den + 1e-16f);
    union { uint4 u; __hip_bfloat16 b[8]; } o;
    #pragma unroll
    for (int j = 0; j < 8; j++) o.b[j] = __float2bfloat16(acc[j] * inv + bias[cb + j]);
    *reinterpret_cast<uint4*>(g + (size_t)n * HC + cb) = o.u;
}

extern "C" void kernel_launch(void* const* d_in, const int* in_sizes, int n_in,
                              void* d_out, int out_size, void* d_ws, size_t ws_size,
                              hipStream_t stream)
{
    const float* x_in     = (const float*)d_in[0];
    const int*   ei       = (const int*)d_in[1];
    const float* ea       = (const float*)d_in[2];
    const float* ln1_g    = (const float*)d_in[3];
    const float* ln1_b    = (const float*)d_in[4];
    const float* gat_W    = (const float*)d_in[5];
    const float* att_src  = (const float*)d_in[6];
    const float* att_dst  = (const float*)d_in[7];
    const float* edge_W   = (const float*)d_in[8];
    const float* att_edge = (const float*)d_in[9];
    const float* gat_bias = (const float*)d_in[10];
    const float* qf_W     = (const float*)d_in[11];
    const float* qf_b     = (const float*)d_in[12];
    const float* ln2_g    = (const float*)d_in[13];
    const float* ln2_b    = (const float*)d_in[14];
    const float* ff_W1    = (const float*)d_in[15];
    const float* ff_b1    = (const float*)d_in[16];
    const float* ff_W2    = (const float*)d_in[17];
    const float* ff_b2    = (const float*)d_in[18];
    float* x = (float*)d_out;

    char* ws = (char*)d_ws;
    size_t o = 0;
    auto alloc = [&](size_t b) { size_t r = o; o += (b + 255) & ~(size_t)255; return r; };
    __hip_bfloat16*  h_ln  = (__hip_bfloat16*)(ws + alloc((size_t)M_PAD * DIM * 2));
    __hip_bfloat16*  h2    = (__hip_bfloat16*)(ws + alloc((size_t)N_NODES * HC * 2));
    __hip_bfloat16*  gbuf  = (__hip_bfloat16*)(ws + alloc((size_t)M_PAD * HC * 2));
    float*           asrc  = (float*)(ws + alloc((size_t)N_NODES * 4 * 4));
    float*           adst  = (float*)(ws + alloc((size_t)N_NODES * 4 * 4));
    float*           ae4   = (float*)(ws + alloc(256));
    int*             deg   = (int*)(ws + alloc((size_t)(N_NODES + 1) * 4));
    int*             off   = (int*)(ws + alloc((size_t)(N_NODES + 1) * 4));
    int*             cur   = (int*)(ws + alloc((size_t)N_NODES * 4));
    int*             scsr  = (int*)(ws + alloc((size_t)N_EDGES * 4));
    float*           eacsr = (float*)(ws + alloc((size_t)N_EDGES * 4));
    __hip_bfloat16* Wt[DEPTH_L][4];
    for (int d = 0; d < DEPTH_L; ++d)
        for (int j = 0; j < 4; ++j)
            Wt[d][j] = (__hip_bfloat16*)(ws + alloc((size_t)65536 * 2));

    const int* srcA = ei;
    const int* dstA = ei + N_EDGES;

    hipMemcpyAsync(x, x_in, (size_t)N_NODES * DIM * 4, hipMemcpyDeviceToDevice, stream);

    for (int d = 0; d < DEPTH_L; ++d) {
        k_wcvt<<<256, 256, 0, stream>>>(gat_W + (size_t)d * DIM * HC,  Wt[d][0], DIM, HC);
        k_wcvt<<<256, 256, 0, stream>>>(qf_W  + (size_t)d * HC * DIM,  Wt[d][1], HC, DIM);
        k_wcvt<<<256, 256, 0, stream>>>(ff_W1 + (size_t)d * DIM * MLP_DIM, Wt[d][2], DIM, MLP_DIM);
        k_wcvt<<<256, 256, 0, stream>>>(ff_W2 + (size_t)d * MLP_DIM * DIM, Wt[d][3], MLP_DIM, DIM);
    }

    // CSR by dst (edges identical across layers)
    hipMemsetAsync(deg, 0, (size_t)(N_NODES + 1) * 4, stream);
    k_hist<<<(N_EDGES + 255) / 256, 256, 0, stream>>>(dstA, deg);
    k_scan<<<1, 1024, 0, stream>>>(deg, off, N_NODES);
    k_cursor<<<(N_NODES + 255) / 256, 256, 0, stream>>>(off, cur);
    k_fill<<<(N_EDGES + 255) / 256, 256, 0, stream>>>(srcA, dstA, ea, cur, scsr, eacsr);

    const int MB = (N_NODES + 127) / 128;   // 313
    const int MB64 = N_NODES / 64;          // 625
    for (int d = 0; d < DEPTH_L; ++d) {
        hipMemsetAsync(asrc, 0, (size_t)N_NODES * 16, stream);
        hipMemsetAsync(adst, 0, (size_t)N_NODES * 16, stream);
        // PreNorm + GAT
        k_ln<<<N_NODES / 4, 256, 0, stream>>>(x, ln1_g + d * DIM, ln1_b + d * DIM, h_ln, N_NODES);
        dim3 g1(MB, HC / 128);
        k_mm<0, 128, 128><<<g1, 256, 0, stream>>>((const short*)h_ln, (const short*)Wt[d][0],
            nullptr, nullptr, h2,
            att_src + (size_t)d * HC, att_dst + (size_t)d * HC, asrc, adst,
            N_NODES, HC, DIM);
        k_ae<<<1, 256, 0, stream>>>(edge_W + d * HC, att_edge + d * NHEAD * CHEAD, ae4);
        k_agg<<<N_NODES / 4, 256, 0, stream>>>(off, scsr, eacsr, asrc, adst, ae4, h2,
            gat_bias + d * HC, gbuf);
        k_mm<2, 64, 64><<<dim3(MB64, 1), 256, 0, stream>>>((const short*)gbuf, (const short*)Wt[d][1],
            qf_b + d * DIM, x, x, nullptr, nullptr, nullptr, nullptr, N_NODES, DIM, HC);
        // PreNorm + FF
        k_ln<<<N_NODES / 4, 256, 0, stream>>>(x, ln2_g + d * DIM, ln2_b + d * DIM, h_ln, N_NODES);
        k_mm<1, 128, 128><<<g1, 256, 0, stream>>>((const short*)h_ln, (const short*)Wt[d][2],
            ff_b1 + d * MLP_DIM, nullptr, gbuf, nullptr, nullptr, nullptr, nullptr,
            N_NODES, MLP_DIM, DIM);
        k_mm<2, 64, 64><<<dim3(MB64, 1), 256, 0, stream>>>((const short*)gbuf, (const short*)Wt[d][3],
            ff_b2 + d * DIM, x, x, nullptr, nullptr, nullptr, nullptr, N_NODES, DIM, MLP_DIM);
    }
}

// Round 5
// 511.296 us; speedup vs baseline: 1.2996x; 1.1040x over previous
//
#include <hip/hip_runtime.h>
#include <hip/hip_bf16.h>

#define N_NODES 40000
#define M_PAD   40064
#define N_EDGES 320000
#define DIM 128
#define HC 512
#define NHEAD 4
#define CHEAD 128
#define DEPTH_L 2
#define MLP_DIM 512

typedef __attribute__((ext_vector_type(8))) short short8;
typedef __attribute__((ext_vector_type(4))) float f32x4;

static __device__ __forceinline__ void gload_lds16(const void* g, void* l)
{
    __builtin_amdgcn_global_load_lds(
        (const __attribute__((address_space(1))) unsigned int*)g,
        (__attribute__((address_space(3))) unsigned int*)l,
        16, 0, 0);
}

// ---------------- LayerNorm: one wave per row, bf16 output -------------------
__global__ __launch_bounds__(256) void k_ln(const float* __restrict__ x,
                                            const float* __restrict__ gma,
                                            const float* __restrict__ bta,
                                            __hip_bfloat16* __restrict__ out, int M)
{
    int row = blockIdx.x * 4 + (threadIdx.x >> 6);
    int lane = threadIdx.x & 63;
    if (row >= M) return;
    float2 v = *reinterpret_cast<const float2*>(x + (size_t)row * DIM + lane * 2);
    float s = v.x + v.y, sq = v.x * v.x + v.y * v.y;
    #pragma unroll
    for (int d = 32; d; d >>= 1) { s += __shfl_xor(s, d); sq += __shfl_xor(sq, d); }
    float mean = s * (1.f / DIM);
    float var = sq * (1.f / DIM) - mean * mean;
    float rs = rsqrtf(var + 1e-5f);
    int c = lane * 2;
    union { __hip_bfloat16 b[2]; unsigned int u; } p;
    p.b[0] = __float2bfloat16((v.x - mean) * rs * gma[c] + bta[c]);
    p.b[1] = __float2bfloat16((v.y - mean) * rs * gma[c + 1] + bta[c + 1]);
    *reinterpret_cast<unsigned int*>(out + (size_t)row * DIM + c) = p.u;
}

// ---------------- weight convert + transpose: W[K][N] f32 -> Wt[N][K] bf16 ---
__global__ __launch_bounds__(256) void k_wcvt(const float* __restrict__ W,
                                              __hip_bfloat16* __restrict__ Wt,
                                              int K, int N)
{
    int i = blockIdx.x * 256 + threadIdx.x;
    if (i < K * N) {
        int n = i / K, k = i % K;
        Wt[i] = __float2bfloat16(W[(size_t)k * N + n]);
    }
}

// ---------------- skinny-K GEMM (K=128): A in registers, B in LDS ------------
// Block = 128 rows x 128-col stripe. 4 waves, each 32 rows x 128 cols.
// One barrier total (B stage); A frags load global->VGPR directly.
// MODE: 0 = bf16 out + fused att dots (plain stores)   1 = bf16 out, bias+gelu
template <int MODE>
__global__ __launch_bounds__(256) void k_mmr(const short* __restrict__ A,
                                             const short* __restrict__ Bt,
                                             const float* __restrict__ bias,
                                             void* __restrict__ Cout,
                                             const float* __restrict__ av,
                                             const float* __restrict__ dv,
                                             float* __restrict__ asrcO,
                                             float* __restrict__ adstO,
                                             int M, int N)
{
    __shared__ __align__(16) short Bls[128 * 128];   // 32 KB
    const int tid = threadIdx.x;
    const int lane = tid & 63;
    const int w = tid >> 6;
    const int lrow = lane & 15;
    const int lk = lane >> 4;
    const int n0 = blockIdx.x * 128;
    const int m0 = blockIdx.y * 128;
    const int mw = m0 + w * 32;

    // stage B stripe: 128 rows x 16 chunks, swizzled slot = g ^ (r&15)
    #pragma unroll
    for (int c0 = 0; c0 < 2048; c0 += 256) {
        int c = c0 + tid;
        int wb = c0 + (w << 6);
        int r = c >> 4, gq = c & 15, gp = gq ^ (r & 15);
        gload_lds16(Bt + (size_t)(n0 + r) * 128 + gp * 8, &Bls[wb * 8]);
    }

    // A fragments: global -> registers (16B contiguous per lane)
    short8 af[2][4];
    #pragma unroll
    for (int fi = 0; fi < 2; ++fi)
        #pragma unroll
        for (int ks = 0; ks < 4; ++ks)
            af[fi][ks] = *reinterpret_cast<const short8*>(
                A + (size_t)(mw + fi * 16 + lrow) * 128 + ks * 32 + lk * 8);

    __syncthreads();

    f32x4 acc[2][8] = {};
    #pragma unroll
    for (int ks = 0; ks < 4; ++ks) {
        short8 bf[8];
        #pragma unroll
        for (int fj = 0; fj < 8; ++fj) {
            int r = fj * 16 + lrow;
            int g = ks * 4 + lk;
            bf[fj] = *reinterpret_cast<const short8*>(
                &Bls[r * 128 + ((g ^ (r & 15)) * 8)]);
        }
        #pragma unroll
        for (int fi = 0; fi < 2; ++fi)
            #pragma unroll
            for (int fj = 0; fj < 8; ++fj)
                acc[fi][fj] = __builtin_amdgcn_mfma_f32_16x16x32_bf16(
                    af[fi][ks], bf[fj], acc[fi][fj], 0, 0, 0);
    }

    // epilogue: C/D layout col = lane&15, row = (lane>>4)*4 + p
    #pragma unroll
    for (int fi = 0; fi < 2; ++fi) {
        #pragma unroll
        for (int fj = 0; fj < 8; ++fj) {
            #pragma unroll
            for (int p = 0; p < 4; ++p) {
                int m = mw + fi * 16 + lk * 4 + p;
                int n = n0 + fj * 16 + lrow;
                if (m >= M) continue;
                float v = acc[fi][fj][p];
                if (MODE == 0) {
                    ((__hip_bfloat16*)Cout)[(size_t)m * N + n] = __float2bfloat16(v);
                } else {
                    v += bias[n];
                    float u = v;
                    v = 0.5f * u * (1.f + tanhf(0.7978845608f * (u + 0.044715f * u * u * u)));
                    ((__hip_bfloat16*)Cout)[(size_t)m * N + n] = __float2bfloat16(v);
                }
            }
        }
    }

    // fused per-node attention dots: full head covered by this wave -> plain store
    if (MODE == 0) {
        float avv[8], dvv[8];
        #pragma unroll
        for (int fj = 0; fj < 8; ++fj) {
            int col = n0 + fj * 16 + lrow;
            avv[fj] = av[col];
            dvv[fj] = dv[col];
        }
        int hh = n0 >> 7;
        #pragma unroll
        for (int fi = 0; fi < 2; ++fi) {
            #pragma unroll
            for (int p = 0; p < 4; ++p) {
                int m = mw + fi * 16 + lk * 4 + p;
                float s1 = 0.f, s2 = 0.f;
                #pragma unroll
                for (int fj = 0; fj < 8; ++fj) {
                    s1 += acc[fi][fj][p] * avv[fj];
                    s2 += acc[fi][fj][p] * dvv[fj];
                }
                #pragma unroll
                for (int d = 1; d < 16; d <<= 1) {
                    s1 += __shfl_xor(s1, d);
                    s2 += __shfl_xor(s2, d);
                }
                if (lrow == 0 && m < M) {
                    asrcO[m * 4 + hh] = s1;
                    adstO[m * 4 + hh] = s2;
                }
            }
        }
    }
}

// ---------------- pipelined GEMM for K=512 shapes: BM=128, BK=64 -------------
// MODE 2 = f32 out, bias+resid
template <int MODE, int BMt, int BKt>
__global__ __launch_bounds__(256) void k_mm(const short* __restrict__ A,
                                            const short* __restrict__ Bt,
                                            const float* __restrict__ bias,
                                            const float* __restrict__ resid,
                                            void* __restrict__ Cout,
                                            int M, int N, int K)
{
    constexpr int FI = BMt / 32;
    constexpr int KS = BKt / 32;
    constexpr int CPR = BKt / 8;
    constexpr int ACH = BMt * CPR;
    constexpr int BCH = 128 * CPR;
    __shared__ __align__(16) short Als[BMt * BKt];
    __shared__ __align__(16) short Bls[128 * BKt];
    const int tid = threadIdx.x;
    const int lane = tid & 63;
    const int w = tid >> 6;
    const int wr = w >> 1, wc = w & 1;
    const int lrow = lane & 15;
    const int lk = lane >> 4;
    const int m0 = blockIdx.x * BMt;
    const int n0 = blockIdx.y * 128;

    f32x4 acc[FI][4] = {};

    for (int kt = 0; kt < K; kt += BKt) {
        #pragma unroll
        for (int c0 = 0; c0 < ACH + BCH; c0 += 256) {
            int c = c0 + tid;
            int wb = c0 + (w << 6);
            if (wb < ACH) {
                int r = c / CPR, gq = c % CPR, gp = gq ^ (r & (CPR - 1));
                gload_lds16(A + (size_t)(m0 + r) * K + kt + gp * 8, &Als[wb * 8]);
            } else {
                int cc = c - ACH;
                int r = cc / CPR, gq = cc % CPR, gp = gq ^ (r & (CPR - 1));
                gload_lds16(Bt + (size_t)(n0 + r) * K + kt + gp * 8,
                            &Bls[(wb - ACH) * 8]);
            }
        }
        __syncthreads();

        #pragma unroll
        for (int ks = 0; ks < KS; ++ks) {
            short8 af[FI], bf[4];
            #pragma unroll
            for (int fi = 0; fi < FI; ++fi) {
                int r = wr * (FI * 16) + fi * 16 + lrow;
                int g = ks * 4 + lk;
                af[fi] = *reinterpret_cast<const short8*>(
                    &Als[r * BKt + (g ^ (r & (CPR - 1))) * 8]);
            }
            #pragma unroll
            for (int fj = 0; fj < 4; ++fj) {
                int r = wc * 64 + fj * 16 + lrow;
                int g = ks * 4 + lk;
                bf[fj] = *reinterpret_cast<const short8*>(
                    &Bls[r * BKt + (g ^ (r & (CPR - 1))) * 8]);
            }
            #pragma unroll
            for (int fi = 0; fi < FI; ++fi)
                #pragma unroll
                for (int fj = 0; fj < 4; ++fj)
                    acc[fi][fj] = __builtin_amdgcn_mfma_f32_16x16x32_bf16(
                        af[fi], bf[fj], acc[fi][fj], 0, 0, 0);
        }
        if (kt + BKt < K) __syncthreads();
    }

    #pragma unroll
    for (int fi = 0; fi < FI; ++fi) {
        #pragma unroll
        for (int fj = 0; fj < 4; ++fj) {
            #pragma unroll
            for (int p = 0; p < 4; ++p) {
                int m = m0 + wr * (FI * 16) + fi * 16 + lk * 4 + p;
                int n = n0 + wc * 64 + fj * 16 + lrow;
                if (m >= M) continue;
                float v = acc[fi][fj][p] + bias[n] + resid[(size_t)m * N + n];
                ((float*)Cout)[(size_t)m * N + n] = v;
            }
        }
    }
}

__global__ void k_ae(const float* __restrict__ We, const float* __restrict__ a_edge,
                     float* __restrict__ ae)
{
    int h = threadIdx.x >> 6, lane = threadIdx.x & 63;
    float2 w = *reinterpret_cast<const float2*>(We + h * CHEAD + lane * 2);
    float2 a = *reinterpret_cast<const float2*>(a_edge + h * CHEAD + lane * 2);
    float s = w.x * a.x + w.y * a.y;
    #pragma unroll
    for (int d = 32; d; d >>= 1) s += __shfl_xor(s, d);
    if (lane == 0) ae[h] = s;
}

// ---------------- CSR build ---------------------------------------------------
__global__ void k_hist(const int* __restrict__ dst, int* __restrict__ deg)
{
    int e = blockIdx.x * 256 + threadIdx.x;
    if (e < N_EDGES) atomicAdd(&deg[dst[e]], 1);
}

__global__ __launch_bounds__(1024) void k_scan(const int* __restrict__ deg,
                                               int* __restrict__ off, int n)
{
    __shared__ int wsum[16];
    __shared__ int carry;
    int t = threadIdx.x, lane = t & 63, w = t >> 6;
    if (t == 0) carry = 0;
    __syncthreads();
    for (int base = 0; base < n; base += 1024) {
        int i = base + t;
        int v = (i < n) ? deg[i] : 0;
        int s = v;
        #pragma unroll
        for (int d = 1; d < 64; d <<= 1) {
            int u = __shfl_up(s, d);
            if (lane >= d) s += u;
        }
        if (lane == 63) wsum[w] = s;
        __syncthreads();
        int wpre = 0;
        for (int j = 0; j < w; j++) wpre += wsum[j];
        int c0 = carry;
        if (i < n) off[i] = c0 + wpre + s - v;
        __syncthreads();
        if (t == 1023) carry = c0 + wpre + s;
        __syncthreads();
    }
    if (t == 0) off[n] = carry;
}

__global__ void k_cursor(const int* __restrict__ off, int* __restrict__ cur)
{
    int n = blockIdx.x * 256 + threadIdx.x;
    if (n < N_NODES) cur[n] = off[n];
}

__global__ void k_fill(const int* __restrict__ src, const int* __restrict__ dst,
                       const float* __restrict__ ea, int* __restrict__ cur,
                       int* __restrict__ scsr, float* __restrict__ eacsr)
{
    int e = blockIdx.x * 256 + threadIdx.x;
    if (e < N_EDGES) {
        int p = atomicAdd(&cur[dst[e]], 1);
        scsr[p] = src[e];
        eacsr[p] = ea[e];
    }
}

// ---------------- fused alpha + softmax + aggregate: 4 nodes / block ----------
__global__ __launch_bounds__(256) void k_agg(const int* __restrict__ off,
                                             const int* __restrict__ scsr,
                                             const float* __restrict__ eacsr,
                                             const float* __restrict__ asrc,
                                             const float* __restrict__ adst,
                                             const float* __restrict__ ae4,
                                             const __hip_bfloat16* __restrict__ h2,
                                             const float* __restrict__ bias,
                                             __hip_bfloat16* __restrict__ g)
{
    int n = blockIdx.x * 4 + (threadIdx.x >> 6);
    int lane = threadIdx.x & 63;
    int h = lane >> 4;
    int cb = lane * 8;
    int e0 = off[n], e1 = off[n + 1];
    float adh = adst[n * 4 + h];
    float aeh = ae4[h];
    float den = 0.f;
    float acc[8] = {0, 0, 0, 0, 0, 0, 0, 0};
    int i = e0;
    for (; i + 1 < e1; i += 2) {
        int s0 = scsr[i], s1 = scsr[i + 1];
        float ea0 = eacsr[i], ea1 = eacsr[i + 1];
        float a0 = asrc[s0 * 4 + h], a1 = asrc[s1 * 4 + h];
        uint4 v0 = *reinterpret_cast<const uint4*>(h2 + (size_t)s0 * HC + cb);
        uint4 v1 = *reinterpret_cast<const uint4*>(h2 + (size_t)s1 * HC + cb);
        float al0 = a0 + adh + aeh * ea0; al0 = al0 > 0.f ? al0 : 0.2f * al0;
        float al1 = a1 + adh + aeh * ea1; al1 = al1 > 0.f ? al1 : 0.2f * al1;
        float w0 = __expf(al0), w1 = __expf(al1);
        den += w0 + w1;
        float f[8];
        f[0] = __uint_as_float(v0.x << 16); f[1] = __uint_as_float(v0.x & 0xffff0000u);
        f[2] = __uint_as_float(v0.y << 16); f[3] = __uint_as_float(v0.y & 0xffff0000u);
        f[4] = __uint_as_float(v0.z << 16); f[5] = __uint_as_float(v0.z & 0xffff0000u);
        f[6] = __uint_as_float(v0.w << 16); f[7] = __uint_as_float(v0.w & 0xffff0000u);
        #pragma unroll
        for (int j = 0; j < 8; j++) acc[j] += w0 * f[j];
        f[0] = __uint_as_float(v1.x << 16); f[1] = __uint_as_float(v1.x & 0xffff0000u);
        f[2] = __uint_as_float(v1.y << 16); f[3] = __uint_as_float(v1.y & 0xffff0000u);
        f[4] = __uint_as_float(v1.z << 16); f[5] = __uint_as_float(v1.z & 0xffff0000u);
        f[6] = __uint_as_float(v1.w << 16); f[7] = __uint_as_float(v1.w & 0xffff0000u);
        #pragma unroll
        for (int j = 0; j < 8; j++) acc[j] += w1 * f[j];
    }
    if (i < e1) {
        int s0 = scsr[i];
        float al = asrc[s0 * 4 + h] + adh + aeh * eacsr[i];
        al = al > 0.f ? al : 0.2f * al;
        float w0 = __expf(al);
        den += w0;
        uint4 v0 = *reinterpret_cast<const uint4*>(h2 + (size_t)s0 * HC + cb);
        float f[8];
        f[0] = __uint_as_float(v0.x << 16); f[1] = __uint_as_float(v0.x & 0xffff0000u);
        f[2] = __uint_as_float(v0.y << 16); f[3] = __uint_as_float(v0.y & 0xffff0000u);
        f[4] = __uint_as_float(v0.z << 16); f[5] = __uint_as_float(v0.z & 0xffff0000u);
        f[6] = __uint_as_float(v0.w << 16); f[7] = __uint_as_float(v0.w & 0xffff0000u);
        #pragma unroll
        for (int j = 0; j < 8; j++) acc[j] += w0 * f[j];
    }
    float inv = 1.f / (den + 1e-16f);
    union { uint4 u; __hip_bfloat16 b[8]; } o;
    #pragma unroll
    for (int j = 0; j < 8; j++) o.b[j] = __float2bfloat16(acc[j] * inv + bias[cb + j]);
    *reinterpret_cast<uint4*>(g + (size_t)n * HC + cb) = o.u;
}

extern "C" void kernel_launch(void* const* d_in, const int* in_sizes, int n_in,
                              void* d_out, int out_size, void* d_ws, size_t ws_size,
                              hipStream_t stream)
{
    const float* x_in     = (const float*)d_in[0];
    const int*   ei       = (const int*)d_in[1];
    const float* ea       = (const float*)d_in[2];
    const float* ln1_g    = (const float*)d_in[3];
    const float* ln1_b    = (const float*)d_in[4];
    const float* gat_W    = (const float*)d_in[5];
    const float* att_src  = (const float*)d_in[6];
    const float* att_dst  = (const float*)d_in[7];
    const float* edge_W   = (const float*)d_in[8];
    const float* att_edge = (const float*)d_in[9];
    const float* gat_bias = (const float*)d_in[10];
    const float* qf_W     = (const float*)d_in[11];
    const float* qf_b     = (const float*)d_in[12];
    const float* ln2_g    = (const float*)d_in[13];
    const float* ln2_b    = (const float*)d_in[14];
    const float* ff_W1    = (const float*)d_in[15];
    const float* ff_b1    = (const float*)d_in[16];
    const float* ff_W2    = (const float*)d_in[17];
    const float* ff_b2    = (const float*)d_in[18];
    float* x = (float*)d_out;

    char* ws = (char*)d_ws;
    size_t o = 0;
    auto alloc = [&](size_t b) { size_t r = o; o += (b + 255) & ~(size_t)255; return r; };
    __hip_bfloat16*  h_ln  = (__hip_bfloat16*)(ws + alloc((size_t)M_PAD * DIM * 2));
    __hip_bfloat16*  h2    = (__hip_bfloat16*)(ws + alloc((size_t)N_NODES * HC * 2));
    __hip_bfloat16*  gbuf  = (__hip_bfloat16*)(ws + alloc((size_t)M_PAD * HC * 2));
    float*           asrc  = (float*)(ws + alloc((size_t)N_NODES * 4 * 4));
    float*           adst  = (float*)(ws + alloc((size_t)N_NODES * 4 * 4));
    float*           ae4   = (float*)(ws + alloc(256));
    int*             deg   = (int*)(ws + alloc((size_t)(N_NODES + 1) * 4));
    int*             off   = (int*)(ws + alloc((size_t)(N_NODES + 1) * 4));
    int*             cur   = (int*)(ws + alloc((size_t)N_NODES * 4));
    int*             scsr  = (int*)(ws + alloc((size_t)N_EDGES * 4));
    float*           eacsr = (float*)(ws + alloc((size_t)N_EDGES * 4));
    __hip_bfloat16* Wt[DEPTH_L][4];
    for (int d = 0; d < DEPTH_L; ++d)
        for (int j = 0; j < 4; ++j)
            Wt[d][j] = (__hip_bfloat16*)(ws + alloc((size_t)65536 * 2));

    const int* srcA = ei;
    const int* dstA = ei + N_EDGES;

    hipMemcpyAsync(x, x_in, (size_t)N_NODES * DIM * 4, hipMemcpyDeviceToDevice, stream);

    for (int d = 0; d < DEPTH_L; ++d) {
        k_wcvt<<<256, 256, 0, stream>>>(gat_W + (size_t)d * DIM * HC,  Wt[d][0], DIM, HC);
        k_wcvt<<<256, 256, 0, stream>>>(qf_W  + (size_t)d * HC * DIM,  Wt[d][1], HC, DIM);
        k_wcvt<<<256, 256, 0, stream>>>(ff_W1 + (size_t)d * DIM * MLP_DIM, Wt[d][2], DIM, MLP_DIM);
        k_wcvt<<<256, 256, 0, stream>>>(ff_W2 + (size_t)d * MLP_DIM * DIM, Wt[d][3], MLP_DIM, DIM);
    }

    // CSR by dst (edges identical across layers)
    hipMemsetAsync(deg, 0, (size_t)(N_NODES + 1) * 4, stream);
    k_hist<<<(N_EDGES + 255) / 256, 256, 0, stream>>>(dstA, deg);
    k_scan<<<1, 1024, 0, stream>>>(deg, off, N_NODES);
    k_cursor<<<(N_NODES + 255) / 256, 256, 0, stream>>>(off, cur);
    k_fill<<<(N_EDGES + 255) / 256, 256, 0, stream>>>(srcA, dstA, ea, cur, scsr, eacsr);

    const int MB = (N_NODES + 127) / 128;   // 313
    for (int d = 0; d < DEPTH_L; ++d) {
        // PreNorm + GAT
        k_ln<<<N_NODES / 4, 256, 0, stream>>>(x, ln1_g + d * DIM, ln1_b + d * DIM, h_ln, N_NODES);
        k_mmr<0><<<dim3(4, MB), 256, 0, stream>>>((const short*)h_ln, (const short*)Wt[d][0],
            nullptr, h2, att_src + (size_t)d * HC, att_dst + (size_t)d * HC,
            asrc, adst, N_NODES, HC);
        k_ae<<<1, 256, 0, stream>>>(edge_W + d * HC, att_edge + d * NHEAD * CHEAD, ae4);
        k_agg<<<N_NODES / 4, 256, 0, stream>>>(off, scsr, eacsr, asrc, adst, ae4, h2,
            gat_bias + d * HC, gbuf);
        k_mm<2, 128, 64><<<dim3(MB, 1), 256, 0, stream>>>((const short*)gbuf,
            (const short*)Wt[d][1], qf_b + d * DIM, x, x, N_NODES, DIM, HC);
        // PreNorm + FF
        k_ln<<<N_NODES / 4, 256, 0, stream>>>(x, ln2_g + d * DIM, ln2_b + d * DIM, h_ln, N_NODES);
        k_mmr<1><<<dim3(4, MB), 256, 0, stream>>>((const short*)h_ln, (const short*)Wt[d][2],
            ff_b1 + d * MLP_DIM, gbuf, nullptr, nullptr, nullptr, nullptr, N_NODES, MLP_DIM);
        k_mm<2, 128, 64><<<dim3(MB, 1), 256, 0, stream>>>((const short*)gbuf,
            (const short*)Wt[d][3], ff_b2 + d * DIM, x, x, N_NODES, DIM, MLP_DIM);
    }
}

// Round 6
// 417.994 us; speedup vs baseline: 1.5896x; 1.2232x over previous
//
#include <hip/hip_runtime.h>
#include <hip/hip_bf16.h>

#define N_NODES 40000
#define M_PAD   40064
#define N_EDGES 320000
#define DIM 128
#define HC 512
#define NHEAD 4
#define CHEAD 128
#define DEPTH_L 2
#define MLP_DIM 512

typedef __attribute__((ext_vector_type(8))) short short8;
typedef __attribute__((ext_vector_type(4))) float f32x4;

static __device__ __forceinline__ void gload_lds16(const void* g, void* l)
{
    __builtin_amdgcn_global_load_lds(
        (const __attribute__((address_space(1))) unsigned int*)g,
        (__attribute__((address_space(3))) unsigned int*)l,
        16, 0, 0);
}

// ---------------- LayerNorm (standalone, used once at start) -----------------
__global__ __launch_bounds__(256) void k_ln(const float* __restrict__ x,
                                            const float* __restrict__ gma,
                                            const float* __restrict__ bta,
                                            __hip_bfloat16* __restrict__ out, int M)
{
    int row = blockIdx.x * 4 + (threadIdx.x >> 6);
    int lane = threadIdx.x & 63;
    if (row >= M) return;
    float2 v = *reinterpret_cast<const float2*>(x + (size_t)row * DIM + lane * 2);
    float s = v.x + v.y, sq = v.x * v.x + v.y * v.y;
    #pragma unroll
    for (int d = 32; d; d >>= 1) { s += __shfl_xor(s, d); sq += __shfl_xor(sq, d); }
    float mean = s * (1.f / DIM);
    float var = sq * (1.f / DIM) - mean * mean;
    float rs = rsqrtf(var + 1e-5f);
    int c = lane * 2;
    union { __hip_bfloat16 b[2]; unsigned int u; } p;
    p.b[0] = __float2bfloat16((v.x - mean) * rs * gma[c] + bta[c]);
    p.b[1] = __float2bfloat16((v.y - mean) * rs * gma[c + 1] + bta[c + 1]);
    *reinterpret_cast<unsigned int*>(out + (size_t)row * DIM + c) = p.u;
}

// ---------------- all 8 weight converts in one launch ------------------------
struct WcvtArgs {
    const float* src[8];
    __hip_bfloat16* dst[8];
    int K[8];
    int Nn[8];
};
__global__ __launch_bounds__(256) void k_wcvt8(WcvtArgs a)
{
    int j = blockIdx.y;
    int i = blockIdx.x * 256 + threadIdx.x;
    int K = a.K[j], N = a.Nn[j];
    if (i < K * N) {
        int n = i / K, k = i % K;
        a.dst[j][i] = __float2bfloat16(a.src[j][(size_t)k * N + n]);
    }
}

// ---------------- skinny-K GEMM (K=128): A in registers, B in LDS ------------
// Block = 128 rows x 128-col stripe. 4 waves, each 32 rows x 128 cols.
// MODE: 0 = bf16 out + fused att dots (plain stores)   1 = bf16 out, bias+gelu
template <int MODE>
__global__ __launch_bounds__(256) void k_mmr(const short* __restrict__ A,
                                             const short* __restrict__ Bt,
                                             const float* __restrict__ bias,
                                             void* __restrict__ Cout,
                                             const float* __restrict__ av,
                                             const float* __restrict__ dv,
                                             float* __restrict__ asrcO,
                                             float* __restrict__ adstO,
                                             int M, int N)
{
    __shared__ __align__(16) short Bls[128 * 128];   // 32 KB
    const int tid = threadIdx.x;
    const int lane = tid & 63;
    const int w = tid >> 6;
    const int lrow = lane & 15;
    const int lk = lane >> 4;
    const int n0 = blockIdx.x * 128;
    const int m0 = blockIdx.y * 128;
    const int mw = m0 + w * 32;

    #pragma unroll
    for (int c0 = 0; c0 < 2048; c0 += 256) {
        int c = c0 + tid;
        int wb = c0 + (w << 6);
        int r = c >> 4, gq = c & 15, gp = gq ^ (r & 15);
        gload_lds16(Bt + (size_t)(n0 + r) * 128 + gp * 8, &Bls[wb * 8]);
    }

    short8 af[2][4];
    #pragma unroll
    for (int fi = 0; fi < 2; ++fi)
        #pragma unroll
        for (int ks = 0; ks < 4; ++ks)
            af[fi][ks] = *reinterpret_cast<const short8*>(
                A + (size_t)(mw + fi * 16 + lrow) * 128 + ks * 32 + lk * 8);

    __syncthreads();

    f32x4 acc[2][8] = {};
    #pragma unroll
    for (int ks = 0; ks < 4; ++ks) {
        short8 bf[8];
        #pragma unroll
        for (int fj = 0; fj < 8; ++fj) {
            int r = fj * 16 + lrow;
            int g = ks * 4 + lk;
            bf[fj] = *reinterpret_cast<const short8*>(
                &Bls[r * 128 + ((g ^ (r & 15)) * 8)]);
        }
        #pragma unroll
        for (int fi = 0; fi < 2; ++fi)
            #pragma unroll
            for (int fj = 0; fj < 8; ++fj)
                acc[fi][fj] = __builtin_amdgcn_mfma_f32_16x16x32_bf16(
                    af[fi][ks], bf[fj], acc[fi][fj], 0, 0, 0);
    }

    #pragma unroll
    for (int fi = 0; fi < 2; ++fi) {
        #pragma unroll
        for (int fj = 0; fj < 8; ++fj) {
            #pragma unroll
            for (int p = 0; p < 4; ++p) {
                int m = mw + fi * 16 + lk * 4 + p;
                int n = n0 + fj * 16 + lrow;
                if (m >= M) continue;
                float v = acc[fi][fj][p];
                if (MODE == 0) {
                    ((__hip_bfloat16*)Cout)[(size_t)m * N + n] = __float2bfloat16(v);
                } else {
                    v += bias[n];
                    float u = v;
                    v = 0.5f * u * (1.f + tanhf(0.7978845608f * (u + 0.044715f * u * u * u)));
                    ((__hip_bfloat16*)Cout)[(size_t)m * N + n] = __float2bfloat16(v);
                }
            }
        }
    }

    if (MODE == 0) {
        float avv[8], dvv[8];
        #pragma unroll
        for (int fj = 0; fj < 8; ++fj) {
            int col = n0 + fj * 16 + lrow;
            avv[fj] = av[col];
            dvv[fj] = dv[col];
        }
        int hh = n0 >> 7;
        #pragma unroll
        for (int fi = 0; fi < 2; ++fi) {
            #pragma unroll
            for (int p = 0; p < 4; ++p) {
                int m = mw + fi * 16 + lk * 4 + p;
                float s1 = 0.f, s2 = 0.f;
                #pragma unroll
                for (int fj = 0; fj < 8; ++fj) {
                    s1 += acc[fi][fj][p] * avv[fj];
                    s2 += acc[fi][fj][p] * dvv[fj];
                }
                #pragma unroll
                for (int d = 1; d < 16; d <<= 1) {
                    s1 += __shfl_xor(s1, d);
                    s2 += __shfl_xor(s2, d);
                }
                if (lrow == 0 && m < M) {
                    asrcO[m * 4 + hh] = s1;
                    adstO[m * 4 + hh] = s2;
                }
            }
        }
    }
}

// ---------------- K=512 -> N=128 GEMM with bias+resid (+fused LayerNorm) -----
// BM=64 (grid 625), BK=128, 4 waves x 16 rows x 128 cols. A direct to regs.
// LN: also emit next LayerNorm's bf16 output (full row per 16-lane group).
template <bool LN>
__global__ __launch_bounds__(256) void k_qf(const short* __restrict__ A,
                                            const short* __restrict__ Bt,
                                            const float* __restrict__ bias,
                                            const float* __restrict__ resid,
                                            float* __restrict__ xout,
                                            const float* __restrict__ gma,
                                            const float* __restrict__ bta,
                                            __hip_bfloat16* __restrict__ hout,
                                            int M)
{
    __shared__ __align__(16) short Bls[128 * 128];   // 32 KB
    const int tid = threadIdx.x;
    const int lane = tid & 63;
    const int w = tid >> 6;
    const int lrow = lane & 15;
    const int lk = lane >> 4;
    const int mw = blockIdx.x * 64 + w * 16;

    f32x4 acc[8] = {};

    for (int kt = 0; kt < 512; kt += 128) {
        #pragma unroll
        for (int c0 = 0; c0 < 2048; c0 += 256) {
            int c = c0 + tid;
            int wb = c0 + (w << 6);
            int r = c >> 4, gq = c & 15, gp = gq ^ (r & 15);
            gload_lds16(Bt + (size_t)r * 512 + kt + gp * 8, &Bls[wb * 8]);
        }
        __syncthreads();

        #pragma unroll
        for (int ks = 0; ks < 4; ++ks) {
            short8 af = *reinterpret_cast<const short8*>(
                A + (size_t)(mw + lrow) * 512 + kt + ks * 32 + lk * 8);
            short8 bf[8];
            #pragma unroll
            for (int fj = 0; fj < 8; ++fj) {
                int r = fj * 16 + lrow;
                int g = ks * 4 + lk;
                bf[fj] = *reinterpret_cast<const short8*>(
                    &Bls[r * 128 + ((g ^ (r & 15)) * 8)]);
            }
            #pragma unroll
            for (int fj = 0; fj < 8; ++fj)
                acc[fj] = __builtin_amdgcn_mfma_f32_16x16x32_bf16(
                    af, bf[fj], acc[fj], 0, 0, 0);
        }
        if (kt + 128 < 512) __syncthreads();
    }

    // epilogue: each (lk,p) group of 16 lanes holds one complete 128-col row
    #pragma unroll
    for (int p = 0; p < 4; ++p) {
        int m = mw + lk * 4 + p;
        float v[8], s = 0.f, sq = 0.f;
        #pragma unroll
        for (int fj = 0; fj < 8; ++fj) {
            int n = fj * 16 + lrow;
            v[fj] = acc[fj][p] + bias[n] + resid[(size_t)m * DIM + n];
            s += v[fj]; sq += v[fj] * v[fj];
        }
        #pragma unroll
        for (int fj = 0; fj < 8; ++fj)
            xout[(size_t)m * DIM + fj * 16 + lrow] = v[fj];
        if (LN) {
            #pragma unroll
            for (int d = 1; d < 16; d <<= 1) {
                s += __shfl_xor(s, d);
                sq += __shfl_xor(sq, d);
            }
            float mean = s * (1.f / DIM);
            float var = sq * (1.f / DIM) - mean * mean;
            float rs = rsqrtf(var + 1e-5f);
            #pragma unroll
            for (int fj = 0; fj < 8; ++fj) {
                int n = fj * 16 + lrow;
                hout[(size_t)m * DIM + n] =
                    __float2bfloat16((v[fj] - mean) * rs * gma[n] + bta[n]);
            }
        }
    }
}

__global__ void k_ae(const float* __restrict__ We, const float* __restrict__ a_edge,
                     float* __restrict__ ae)
{
    int h = threadIdx.x >> 6, lane = threadIdx.x & 63;
    float2 w = *reinterpret_cast<const float2*>(We + h * CHEAD + lane * 2);
    float2 a = *reinterpret_cast<const float2*>(a_edge + h * CHEAD + lane * 2);
    float s = w.x * a.x + w.y * a.y;
    #pragma unroll
    for (int d = 32; d; d >>= 1) s += __shfl_xor(s, d);
    if (lane == 0) ae[h] = s;
}

// ---------------- CSR build ---------------------------------------------------
__global__ void k_hist(const int* __restrict__ dst, int* __restrict__ deg)
{
    int e = blockIdx.x * 256 + threadIdx.x;
    if (e < N_EDGES) atomicAdd(&deg[dst[e]], 1);
}

__global__ __launch_bounds__(1024) void k_scan(const int* __restrict__ deg,
                                               int* __restrict__ off, int n)
{
    __shared__ int wsum[16];
    __shared__ int carry;
    int t = threadIdx.x, lane = t & 63, w = t >> 6;
    if (t == 0) carry = 0;
    __syncthreads();
    for (int base = 0; base < n; base += 1024) {
        int i = base + t;
        int v = (i < n) ? deg[i] : 0;
        int s = v;
        #pragma unroll
        for (int d = 1; d < 64; d <<= 1) {
            int u = __shfl_up(s, d);
            if (lane >= d) s += u;
        }
        if (lane == 63) wsum[w] = s;
        __syncthreads();
        int wpre = 0;
        for (int j = 0; j < w; j++) wpre += wsum[j];
        int c0 = carry;
        if (i < n) off[i] = c0 + wpre + s - v;
        __syncthreads();
        if (t == 1023) carry = c0 + wpre + s;
        __syncthreads();
    }
    if (t == 0) off[n] = carry;
}

__global__ void k_cursor(const int* __restrict__ off, int* __restrict__ cur)
{
    int n = blockIdx.x * 256 + threadIdx.x;
    if (n < N_NODES) cur[n] = off[n];
}

__global__ void k_fill(const int* __restrict__ src, const int* __restrict__ dst,
                       const float* __restrict__ ea, int* __restrict__ cur,
                       int* __restrict__ scsr, float* __restrict__ eacsr)
{
    int e = blockIdx.x * 256 + threadIdx.x;
    if (e < N_EDGES) {
        int p = atomicAdd(&cur[dst[e]], 1);
        scsr[p] = src[e];
        eacsr[p] = ea[e];
    }
}

// ---------------- fused alpha + softmax + aggregate: 4 nodes / block ----------
static __device__ __forceinline__ void accum8(float* acc, uint4 v, float w)
{
    acc[0] += w * __uint_as_float(v.x << 16);
    acc[1] += w * __uint_as_float(v.x & 0xffff0000u);
    acc[2] += w * __uint_as_float(v.y << 16);
    acc[3] += w * __uint_as_float(v.y & 0xffff0000u);
    acc[4] += w * __uint_as_float(v.z << 16);
    acc[5] += w * __uint_as_float(v.z & 0xffff0000u);
    acc[6] += w * __uint_as_float(v.w << 16);
    acc[7] += w * __uint_as_float(v.w & 0xffff0000u);
}

__global__ __launch_bounds__(256) void k_agg(const int* __restrict__ off,
                                             const int* __restrict__ scsr,
                                             const float* __restrict__ eacsr,
                                             const float* __restrict__ asrc,
                                             const float* __restrict__ adst,
                                             const float* __restrict__ ae4,
                                             const __hip_bfloat16* __restrict__ h2,
                                             const float* __restrict__ bias,
                                             __hip_bfloat16* __restrict__ g)
{
    int n = blockIdx.x * 4 + (threadIdx.x >> 6);
    int lane = threadIdx.x & 63;
    int h = lane >> 4;
    int cb = lane * 8;
    int e0 = off[n], e1 = off[n + 1];
    float adh = adst[n * 4 + h];
    float aeh = ae4[h];
    float den = 0.f;
    float acc[8] = {0, 0, 0, 0, 0, 0, 0, 0};
    int i = e0;
    for (; i + 3 < e1; i += 4) {
        int s0 = scsr[i], s1 = scsr[i + 1], s2 = scsr[i + 2], s3 = scsr[i + 3];
        float q0 = eacsr[i], q1 = eacsr[i + 1], q2 = eacsr[i + 2], q3 = eacsr[i + 3];
        uint4 v0 = *reinterpret_cast<const uint4*>(h2 + (size_t)s0 * HC + cb);
        uint4 v1 = *reinterpret_cast<const uint4*>(h2 + (size_t)s1 * HC + cb);
        uint4 v2 = *reinterpret_cast<const uint4*>(h2 + (size_t)s2 * HC + cb);
        uint4 v3 = *reinterpret_cast<const uint4*>(h2 + (size_t)s3 * HC + cb);
        float a0 = asrc[s0 * 4 + h], a1 = asrc[s1 * 4 + h];
        float a2 = asrc[s2 * 4 + h], a3 = asrc[s3 * 4 + h];
        float al0 = a0 + adh + aeh * q0; al0 = al0 > 0.f ? al0 : 0.2f * al0;
        float al1 = a1 + adh + aeh * q1; al1 = al1 > 0.f ? al1 : 0.2f * al1;
        float al2 = a2 + adh + aeh * q2; al2 = al2 > 0.f ? al2 : 0.2f * al2;
        float al3 = a3 + adh + aeh * q3; al3 = al3 > 0.f ? al3 : 0.2f * al3;
        float w0 = __expf(al0), w1 = __expf(al1);
        float w2 = __expf(al2), w3 = __expf(al3);
        den += (w0 + w1) + (w2 + w3);
        accum8(acc, v0, w0);
        accum8(acc, v1, w1);
        accum8(acc, v2, w2);
        accum8(acc, v3, w3);
    }
    for (; i < e1; ++i) {
        int s0 = scsr[i];
        float al = asrc[s0 * 4 + h] + adh + aeh * eacsr[i];
        al = al > 0.f ? al : 0.2f * al;
        float w0 = __expf(al);
        den += w0;
        uint4 v0 = *reinterpret_cast<const uint4*>(h2 + (size_t)s0 * HC + cb);
        accum8(acc, v0, w0);
    }
    float inv = 1.f / (den + 1e-16f);
    union { uint4 u; __hip_bfloat16 b[8]; } o;
    #pragma unroll
    for (int j = 0; j < 8; j++) o.b[j] = __float2bfloat16(acc[j] * inv + bias[cb + j]);
    *reinterpret_cast<uint4*>(g + (size_t)n * HC + cb) = o.u;
}

extern "C" void kernel_launch(void* const* d_in, const int* in_sizes, int n_in,
                              void* d_out, int out_size, void* d_ws, size_t ws_size,
                              hipStream_t stream)
{
    const float* x_in     = (const float*)d_in[0];
    const int*   ei       = (const int*)d_in[1];
    const float* ea       = (const float*)d_in[2];
    const float* ln1_g    = (const float*)d_in[3];
    const float* ln1_b    = (const float*)d_in[4];
    const float* gat_W    = (const float*)d_in[5];
    const float* att_src  = (const float*)d_in[6];
    const float* att_dst  = (const float*)d_in[7];
    const float* edge_W   = (const float*)d_in[8];
    const float* att_edge = (const float*)d_in[9];
    const float* gat_bias = (const float*)d_in[10];
    const float* qf_W     = (const float*)d_in[11];
    const float* qf_b     = (const float*)d_in[12];
    const float* ln2_g    = (const float*)d_in[13];
    const float* ln2_b    = (const float*)d_in[14];
    const float* ff_W1    = (const float*)d_in[15];
    const float* ff_b1    = (const float*)d_in[16];
    const float* ff_W2    = (const float*)d_in[17];
    const float* ff_b2    = (const float*)d_in[18];
    float* x = (float*)d_out;

    char* ws = (char*)d_ws;
    size_t o = 0;
    auto alloc = [&](size_t b) { size_t r = o; o += (b + 255) & ~(size_t)255; return r; };
    __hip_bfloat16*  h_ln  = (__hip_bfloat16*)(ws + alloc((size_t)M_PAD * DIM * 2));
    __hip_bfloat16*  h2    = (__hip_bfloat16*)(ws + alloc((size_t)N_NODES * HC * 2));
    __hip_bfloat16*  gbuf  = (__hip_bfloat16*)(ws + alloc((size_t)M_PAD * HC * 2));
    float*           asrc  = (float*)(ws + alloc((size_t)N_NODES * 4 * 4));
    float*           adst  = (float*)(ws + alloc((size_t)N_NODES * 4 * 4));
    float*           ae4   = (float*)(ws + alloc(256));
    int*             deg   = (int*)(ws + alloc((size_t)(N_NODES + 1) * 4));
    int*             off   = (int*)(ws + alloc((size_t)(N_NODES + 1) * 4));
    int*             cur   = (int*)(ws + alloc((size_t)N_NODES * 4));
    int*             scsr  = (int*)(ws + alloc((size_t)N_EDGES * 4));
    float*           eacsr = (float*)(ws + alloc((size_t)N_EDGES * 4));
    __hip_bfloat16* Wt[DEPTH_L][4];
    for (int d = 0; d < DEPTH_L; ++d)
        for (int j = 0; j < 4; ++j)
            Wt[d][j] = (__hip_bfloat16*)(ws + alloc((size_t)65536 * 2));

    const int* srcA = ei;
    const int* dstA = ei + N_EDGES;

    // all weight converts in one launch
    WcvtArgs wa;
    for (int d = 0; d < DEPTH_L; ++d) {
        wa.src[d * 4 + 0] = gat_W + (size_t)d * DIM * HC;      wa.K[d * 4 + 0] = DIM; wa.Nn[d * 4 + 0] = HC;
        wa.src[d * 4 + 1] = qf_W  + (size_t)d * HC * DIM;      wa.K[d * 4 + 1] = HC;  wa.Nn[d * 4 + 1] = DIM;
        wa.src[d * 4 + 2] = ff_W1 + (size_t)d * DIM * MLP_DIM; wa.K[d * 4 + 2] = DIM; wa.Nn[d * 4 + 2] = MLP_DIM;
        wa.src[d * 4 + 3] = ff_W2 + (size_t)d * MLP_DIM * DIM; wa.K[d * 4 + 3] = MLP_DIM; wa.Nn[d * 4 + 3] = DIM;
        for (int j = 0; j < 4; ++j) wa.dst[d * 4 + j] = Wt[d][j];
    }
    k_wcvt8<<<dim3(256, 8), 256, 0, stream>>>(wa);

    // CSR by dst (edges identical across layers)
    hipMemsetAsync(deg, 0, (size_t)(N_NODES + 1) * 4, stream);
    k_hist<<<(N_EDGES + 255) / 256, 256, 0, stream>>>(dstA, deg);
    k_scan<<<1, 1024, 0, stream>>>(deg, off, N_NODES);
    k_cursor<<<(N_NODES + 255) / 256, 256, 0, stream>>>(off, cur);
    k_fill<<<(N_EDGES + 255) / 256, 256, 0, stream>>>(srcA, dstA, ea, cur, scsr, eacsr);

    const int MB = (N_NODES + 127) / 128;   // 313
    const int QB = N_NODES / 64;            // 625

    // initial LayerNorm reads x_in directly (no copy needed; first k_qf uses
    // x_in as residual and writes x)
    k_ln<<<N_NODES / 4, 256, 0, stream>>>(x_in, ln1_g, ln1_b, h_ln, N_NODES);

    for (int d = 0; d < DEPTH_L; ++d) {
        const float* resid0 = (d == 0) ? x_in : x;
        // GAT on h_ln
        k_mmr<0><<<dim3(4, MB), 256, 0, stream>>>((const short*)h_ln, (const short*)Wt[d][0],
            nullptr, h2, att_src + (size_t)d * HC, att_dst + (size_t)d * HC,
            asrc, adst, N_NODES, HC);
        k_ae<<<1, 256, 0, stream>>>(edge_W + d * HC, att_edge + d * NHEAD * CHEAD, ae4);
        k_agg<<<N_NODES / 4, 256, 0, stream>>>(off, scsr, eacsr, asrc, adst, ae4, h2,
            gat_bias + d * HC, gbuf);
        // qf GEMM + resid + fused LN2 -> h_ln
        k_qf<true><<<QB, 256, 0, stream>>>((const short*)gbuf, (const short*)Wt[d][1],
            qf_b + d * DIM, resid0, x, ln2_g + d * DIM, ln2_b + d * DIM, h_ln, N_NODES);
        // FF1 (gelu) on h_ln
        k_mmr<1><<<dim3(4, MB), 256, 0, stream>>>((const short*)h_ln, (const short*)Wt[d][2],
            ff_b1 + d * MLP_DIM, gbuf, nullptr, nullptr, nullptr, nullptr, N_NODES, MLP_DIM);
        // FF2 GEMM + resid (+ fused LN1 of next layer, except at the end)
        if (d + 1 < DEPTH_L) {
            k_qf<true><<<QB, 256, 0, stream>>>((const short*)gbuf, (const short*)Wt[d][3],
                ff_b2 + d * DIM, x, x, ln1_g + (d + 1) * DIM, ln1_b + (d + 1) * DIM,
                h_ln, N_NODES);
        } else {
            k_qf<false><<<QB, 256, 0, stream>>>((const short*)gbuf, (const short*)Wt[d][3],
                ff_b2 + d * DIM, x, x, nullptr, nullptr, nullptr, N_NODES);
        }
    }
}